// Round 1
// baseline (2614.969 us; speedup 1.0000x reference)
//
#include <hip/hip_runtime.h>
#include <math.h>

#pragma clang fp contract(off)

#define NROWS 131072
#define INDIM 64
#define EMBD  64
#define KCODE 1024
#define DENSE 256

// selu matching np: scale * where(x>0, x, alpha*expm1(x)), each op rounded separately
__device__ __forceinline__ float selu_f(float v) {
    float em  = expm1f(v);
    float neg = 1.6732632423543772f * em;
    float r   = v > 0.0f ? v : neg;
    return 1.0507009873554805f * r;
}

// ---------- prep 1: transposes W2 [256,256] -> W2T [j][c], W3 [64,256] -> W3T [c][e] ----------
__global__ void prep_transpose(const float* __restrict__ W2, const float* __restrict__ W3,
                               float* __restrict__ W2T, float* __restrict__ W3T) {
    int id = blockIdx.x * 256 + threadIdx.x;
    if (id < 65536) {
        int c = id >> 8, j = id & 255;
        W2T[j * 256 + c] = W2[id];
    }
    int id2 = id - 65536;
    if (id2 >= 0 && id2 < 16384) {
        int e = id2 >> 8, c = id2 & 255;
        W3T[c * 64 + e] = W3[id2];
    }
}

// ---------- prep 2: decoder table dec_out[k] = decoder(emb[k]), and en[k] = ||emb_k||^2 ----------
__global__ void prep_decoder(const float* __restrict__ emb,
                             const float* __restrict__ Wd1, const float* __restrict__ bd1,
                             const float* __restrict__ Wd2, const float* __restrict__ bd2,
                             const float* __restrict__ Wd3, const float* __restrict__ bd3,
                             float* __restrict__ dec_out, float* __restrict__ en) {
    __shared__ float e[64];
    __shared__ float h1[256];
    __shared__ float h2[256];
    const int t = threadIdx.x; // 256 threads
    for (int kc = 0; kc < 4; ++kc) {
        const int k = blockIdx.x * 4 + kc;
        __syncthreads(); // protect smem reuse across iterations
        if (t < 64) e[t] = emb[k * 64 + t];
        __syncthreads();
        {
            float acc = 0.0f;
            const float* w = Wd1 + t * 64;
            #pragma unroll
            for (int j = 0; j < 64; ++j) acc = __builtin_fmaf(w[j], e[j], acc);
            h1[t] = selu_f(acc + bd1[t]);
        }
        __syncthreads();
        {
            float acc = 0.0f;
            const float* w = Wd2 + t * 256;
            #pragma unroll 8
            for (int j = 0; j < 256; ++j) acc = __builtin_fmaf(w[j], h1[j], acc);
            h2[t] = selu_f(acc + bd2[t]);
        }
        __syncthreads();
        if (t < 64) {
            float acc = 0.0f;
            const float* w = Wd3 + t * 256;
            #pragma unroll 8
            for (int j = 0; j < 256; ++j) acc = __builtin_fmaf(w[j], h2[j], acc);
            dec_out[k * 64 + t] = acc + bd3[t];
        }
        if (t == 0) {
            // numpy pairwise sum (n=64 base case): 8 strided accumulators, then balanced tree
            float r[8];
            #pragma unroll
            for (int u = 0; u < 8; ++u) r[u] = e[u] * e[u];
            #pragma unroll
            for (int i = 8; i < 64; i += 8) {
                #pragma unroll
                for (int u = 0; u < 8; ++u) { float p = e[i + u] * e[i + u]; r[u] = r[u] + p; }
            }
            en[k] = ((r[0] + r[1]) + (r[2] + r[3])) + ((r[4] + r[5]) + (r[6] + r[7]));
        }
    }
}

// ---------- main: encoder (fp32, SGPR-broadcast weights) + argmin + gather ----------
// block = 256 threads = 4 waves, 64 rows/block (lane = row), wave w owns col-slice [64w,64w+64)
__launch_bounds__(256, 2)
__global__ void vqvae_main(const float* __restrict__ x,
                           const float* __restrict__ W1, const float* __restrict__ b1,
                           const float* __restrict__ b2, const float* __restrict__ b3,
                           const float* __restrict__ W2T, const float* __restrict__ W3T,
                           const float* __restrict__ emb, const float* __restrict__ en,
                           const float* __restrict__ dec_out, float* __restrict__ out) {
    __shared__ float smem[16640];       // phase-aliased: x-stage [64][65] -> h1T [256][65] -> zpart [4][64][65]
    __shared__ float cand_s[4][64];
    __shared__ int   cand_k[4][64];
    __shared__ int   ix[64];

    const int t    = threadIdx.x;
    const int wave = t >> 6;
    const int lane = t & 63;            // row within tile
    const int rowbase = blockIdx.x * 64;

    // ---- phase 0: stage x tile coalesced, extract own row to registers
    float xr[64];
    {
        float* xs = smem; // [64][65]
        #pragma unroll
        for (int q = 0; q < 4; ++q) {
            int f4 = t * 4 + q;             // 1024 float4s
            int r = f4 >> 4, c4 = f4 & 15;
            float4 v = *(const float4*)(x + (size_t)(rowbase + r) * 64 + c4 * 4);
            xs[r * 65 + c4 * 4 + 0] = v.x;
            xs[r * 65 + c4 * 4 + 1] = v.y;
            xs[r * 65 + c4 * 4 + 2] = v.z;
            xs[r * 65 + c4 * 4 + 3] = v.w;
        }
        __syncthreads();
        #pragma unroll
        for (int j = 0; j < 64; ++j) xr[j] = xs[lane * 65 + j];
        __syncthreads(); // xs dead, region becomes h1T
    }

    // ---- phase 1: layer1 -> h1T[c][lane], c in wave's slice
    {
        float* h1T = smem; // [256][65]
        for (int cc = 0; cc < 64; cc += 8) {
            float acc[8] = {0.f, 0.f, 0.f, 0.f, 0.f, 0.f, 0.f, 0.f};
            const float* w = W1 + (wave * 64 + cc) * 64; // 8 consecutive rows of We1
            #pragma unroll
            for (int j = 0; j < 64; ++j) {
                #pragma unroll
                for (int u = 0; u < 8; ++u)
                    acc[u] = __builtin_fmaf(w[u * 64 + j], xr[j], acc[u]);
            }
            #pragma unroll
            for (int u = 0; u < 8; ++u) {
                int c = wave * 64 + cc + u;
                h1T[c * 65 + lane] = selu_f(acc[u] + b1[c]);
            }
        }
        __syncthreads();
    }

    // ---- phase 2: fused layer2+layer3: z partial accumulators in registers
    float zacc[64];
    #pragma unroll
    for (int e = 0; e < 64; ++e) zacc[e] = 0.0f;
    {
        const float* h1T = smem;
        for (int cc = 0; cc < 64; cc += 8) {
            float acc[8] = {0.f, 0.f, 0.f, 0.f, 0.f, 0.f, 0.f, 0.f};
            const int c0 = wave * 64 + cc;
            #pragma unroll 4
            for (int j = 0; j < 256; ++j) {
                float hv = h1T[j * 65 + lane];
                const float* w2 = W2T + j * 256 + c0;   // uniform -> s_load
                #pragma unroll
                for (int u = 0; u < 8; ++u)
                    acc[u] = __builtin_fmaf(w2[u], hv, acc[u]);
            }
            #pragma unroll
            for (int u = 0; u < 8; ++u) {
                float h2v = selu_f(acc[u] + b2[c0 + u]);
                const float* w3 = W3T + (c0 + u) * 64;  // uniform -> s_load
                #pragma unroll
                for (int e = 0; e < 64; ++e)
                    zacc[e] = __builtin_fmaf(w3[e], h2v, zacc[e]);
            }
        }
    }
    __syncthreads(); // all waves done reading h1T

    // ---- phase 3: write z partials, cross-wave reduce, z regs + A = ||z||^2 (numpy pairwise)
    {
        float* zp = smem; // [4*64][65]
        #pragma unroll
        for (int e = 0; e < 64; ++e) zp[(wave * 64 + e) * 65 + lane] = zacc[e];
    }
    __syncthreads();
    float z[64];
    float A;
    {
        const float* zp = smem;
        #pragma unroll
        for (int e = 0; e < 64; ++e) {
            float s01 = zp[e * 65 + lane] + zp[(64 + e) * 65 + lane];
            float s23 = zp[(128 + e) * 65 + lane] + zp[(192 + e) * 65 + lane];
            z[e] = (s01 + s23) + b3[e];   // bias added after full dot, matching np
        }
        float r[8];
        #pragma unroll
        for (int u = 0; u < 8; ++u) r[u] = z[u] * z[u];
        #pragma unroll
        for (int i = 8; i < 64; i += 8) {
            #pragma unroll
            for (int u = 0; u < 8; ++u) { float p = z[i + u] * z[i + u]; r[u] = r[u] + p; }
        }
        A = ((r[0] + r[1]) + (r[2] + r[3])) + ((r[4] + r[5]) + (r[6] + r[7]));
    }

    // ---- phase 4: scores over wave's k-slice; d = (A - 2*z.e) + ||e||^2, first-min
    float best = 3.4e38f;
    int   bk   = wave * 256;
    {
        const float* eb  = emb + (size_t)wave * 256 * 64;
        const float* enw = en + wave * 256;
        for (int kk = 0; kk < 256; ++kk) {
            const float* ek = eb + kk * 64;  // uniform -> s_load
            float d0 = 0.f, d1 = 0.f, d2 = 0.f, d3 = 0.f;
            #pragma unroll
            for (int j = 0; j < 64; j += 4) {
                d0 = __builtin_fmaf(z[j + 0], ek[j + 0], d0);
                d1 = __builtin_fmaf(z[j + 1], ek[j + 1], d1);
                d2 = __builtin_fmaf(z[j + 2], ek[j + 2], d2);
                d3 = __builtin_fmaf(z[j + 3], ek[j + 3], d3);
            }
            float dot = (d0 + d1) + (d2 + d3);
            float tt  = __builtin_fmaf(-2.0f, dot, A); // == rnd(A - 2B), 2B exact
            float s   = tt + enw[kk];
            if (s < best) { best = s; bk = wave * 256 + kk; }
        }
    }

    // ---- phase 5: cross-wave argmin combine (ascending wave => first-min), write idx
    cand_s[wave][lane] = best;
    cand_k[wave][lane] = bk;
    __syncthreads();
    if (t < 64) {
        float s0 = cand_s[0][t];
        int   k0 = cand_k[0][t];
        #pragma unroll
        for (int w2 = 1; w2 < 4; ++w2) {
            float sw = cand_s[w2][t];
            if (sw < s0) { s0 = sw; k0 = cand_k[w2][t]; }
        }
        ix[t] = k0;
        out[(size_t)NROWS * 64 + rowbase + t] = (float)k0; // idx as float
    }
    __syncthreads();

    // ---- phase 6: recon = dec_out[idx] gather, coalesced store
    #pragma unroll
    for (int q = 0; q < 4; ++q) {
        int f4 = t * 4 + q;
        int r = f4 >> 4, c4 = f4 & 15;
        float4 v = *(const float4*)(dec_out + (size_t)ix[r] * 64 + c4 * 4);
        *(float4*)(out + (size_t)(rowbase + r) * 64 + c4 * 4) = v;
    }
}

extern "C" void kernel_launch(void* const* d_in, const int* in_sizes, int n_in,
                              void* d_out, int out_size, void* d_ws, size_t ws_size,
                              hipStream_t stream) {
    const float* x   = (const float*)d_in[0];
    const float* We1 = (const float*)d_in[1];
    const float* be1 = (const float*)d_in[2];
    const float* We2 = (const float*)d_in[3];
    const float* be2 = (const float*)d_in[4];
    const float* We3 = (const float*)d_in[5];
    const float* be3 = (const float*)d_in[6];
    const float* emb = (const float*)d_in[7];
    const float* Wd1 = (const float*)d_in[8];
    const float* bd1 = (const float*)d_in[9];
    const float* Wd2 = (const float*)d_in[10];
    const float* bd2 = (const float*)d_in[11];
    const float* Wd3 = (const float*)d_in[12];
    const float* bd3 = (const float*)d_in[13];
    float* out = (float*)d_out;

    char* ws = (char*)d_ws;
    float* dec_out = (float*)(ws);            // 1024*64*4   = 256 KB
    float* W2T     = (float*)(ws + 262144);   // 256*256*4   = 256 KB
    float* W3T     = (float*)(ws + 524288);   // 256*64*4    =  64 KB
    float* en      = (float*)(ws + 589824);   // 1024*4      =   4 KB

    prep_transpose<<<320, 256, 0, stream>>>(We2, We3, W2T, W3T);
    prep_decoder<<<256, 256, 0, stream>>>(emb, Wd1, bd1, Wd2, bd2, Wd3, bd3, dec_out, en);
    vqvae_main<<<NROWS / 64, 256, 0, stream>>>(x, We1, be1, be2, be3, W2T, W3T, emb, en,
                                               dec_out, out);
}